// Round 14
// baseline (337.465 us; speedup 1.0000x reference)
//
#include <hip/hip_runtime.h>
#include <stdint.h>

typedef __bf16 bf16_t;
typedef __bf16 bf16x4 __attribute__((ext_vector_type(4)));
typedef __bf16 bf16x8 __attribute__((ext_vector_type(8)));
typedef float f32x4 __attribute__((ext_vector_type(4)));
typedef unsigned int u32;

// Problem constants (B, N, L, D, H) = (8, 128, 4096, 1024, 16)
constexpr int CB = 8, CN = 128, CL = 4096, CD = 1024, CH = 16, CDh = 64;

#define BAR()                                    \
  do {                                           \
    __asm__ volatile("" ::: "memory");           \
    __builtin_amdgcn_s_barrier();                \
    __asm__ volatile("" ::: "memory");           \
  } while (0)

__device__ __forceinline__ bf16x4 cvt4(float4 v) {
  bf16x4 r;
  r[0] = (__bf16)v.x; r[1] = (__bf16)v.y; r[2] = (__bf16)v.z; r[3] = (__bf16)v.w;
  return r;
}

// async global->LDS, 16 B per lane. LDS dest is wave-uniform base + lane*16.
__device__ __forceinline__ void async16(void* lds, const void* g) {
  __builtin_amdgcn_global_load_lds(
      (const __attribute__((address_space(1))) u32*)g,
      (__attribute__((address_space(3))) u32*)lds, 16, 0, 0);
}

// f32 -> bf16 elementwise, n4 = elems/4 (plan-B path)
__global__ __launch_bounds__(256) void cvt_f32_bf16(const float* __restrict__ in,
                                                    bf16_t* __restrict__ outp, int n4) {
  int i = (int)blockIdx.x * 256 + (int)threadIdx.x;
  if (i < n4) {
    float4 v = reinterpret_cast<const float4*>(in)[i];
    reinterpret_cast<bf16x4*>(outp)[i] = cvt4(v);
  }
}

// ---------------------------------------------------------------------------
// fuse1 (round 12, proven): ONE dispatch for three independent jobs.
//  blocks [0,64): Q-projection qh = bf16(q @ Wq^T) (round-1 body).
//  blocks [64, 64+4096): Wq,Wk,Wv,Wo -> wb4 (bf16).
//  blocks [64+4096, +65536): k,v -> kc,vc (bf16).
// ---------------------------------------------------------------------------
__global__ __launch_bounds__(256)
void fuse1(const float* __restrict__ q, const float* __restrict__ k,
           const float* __restrict__ v, const float* __restrict__ Wq,
           const float* __restrict__ Wk, const float* __restrict__ Wv,
           const float* __restrict__ Wo, bf16_t* __restrict__ qh,
           bf16_t* __restrict__ wb4, bf16_t* __restrict__ kc,
           bf16_t* __restrict__ vc) {
  const int bid = (int)blockIdx.x;
  const int t = (int)threadIdx.x;

  if (bid >= 64) {
    const int W4 = CD * CD / 4;
    const int A4_kv = CB * CL * CD / 4;
    if (bid < 64 + 4096) {
      const int widx = bid - 64;
      const int which = widx >> 10;
      const float* srcs[4] = {Wq, Wk, Wv, Wo};
      const int i = (widx & 1023) * 256 + t;
      reinterpret_cast<bf16x4*>(wb4 + (size_t)which * CD * CD)[i] =
          cvt4(reinterpret_cast<const float4*>(srcs[which])[i]);
    } else {
      const int i = (bid - 64 - 4096) * 256 + t;
      if (i < A4_kv)
        reinterpret_cast<bf16x4*>(kc)[i] = cvt4(reinterpret_cast<const float4*>(k)[i]);
      else
        reinterpret_cast<bf16x4*>(vc)[i - A4_kv] =
            cvt4(reinterpret_cast<const float4*>(v)[i - A4_kv]);
    }
    return;
  }

  __shared__ bf16_t As[128][40];
  __shared__ bf16_t Bs[128][40];
  const int lane = t & 63, wv = t >> 6;
  const int wm = (wv >> 1) * 64, wn = (wv & 1) * 64;
  const int brow = (bid >> 3) * 128, bcol = (bid & 7) * 128;
  const int fr = lane & 15, fk = (lane >> 4) * 8;
  const int K = CD;

  const f32x4 z = {0.f, 0.f, 0.f, 0.f};
  f32x4 acc[4][4];
#pragma unroll
  for (int m = 0; m < 4; ++m)
#pragma unroll
    for (int n = 0; n < 4; ++n) acc[m][n] = z;

  for (int k0 = 0; k0 < K; k0 += 32) {
    {
      const int tr = t >> 3, tc = (t & 7) * 4;
#pragma unroll
      for (int p = 0; p < 4; ++p) {
        const int r = p * 32 + tr;
        float4 va = *reinterpret_cast<const float4*>(q + (size_t)(brow + r) * K + k0 + tc);
        *reinterpret_cast<bf16x4*>(&As[r][tc]) = cvt4(va);
        float4 vb = *reinterpret_cast<const float4*>(Wq + (size_t)(bcol + r) * K + k0 + tc);
        *reinterpret_cast<bf16x4*>(&Bs[r][tc]) = cvt4(vb);
      }
    }
    __syncthreads();
    bf16x8 af[4], bfr[4];
#pragma unroll
    for (int m = 0; m < 4; ++m)
      af[m] = *reinterpret_cast<const bf16x8*>(&As[wm + m * 16 + fr][fk]);
#pragma unroll
    for (int n = 0; n < 4; ++n)
      bfr[n] = *reinterpret_cast<const bf16x8*>(&Bs[wn + n * 16 + fr][fk]);
#pragma unroll
    for (int m = 0; m < 4; ++m)
#pragma unroll
      for (int n = 0; n < 4; ++n)
        acc[m][n] = __builtin_amdgcn_mfma_f32_16x16x32_bf16(af[m], bfr[n], acc[m][n], 0, 0, 0);
    __syncthreads();
  }
  const int rb = (lane >> 4) * 4;
#pragma unroll
  for (int m = 0; m < 4; ++m)
#pragma unroll
    for (int n = 0; n < 4; ++n)
#pragma unroll
      for (int r = 0; r < 4; ++r) {
        const int row = brow + wm + m * 16 + rb + r;
        const int col = bcol + wn + n * 16 + fr;
        qh[(size_t)row * CD + col] = (__bf16)acc[m][n][r];
      }
}

// ---------------------------------------------------------------------------
// 256x256xBK64 bf16 GEMM — round-14: 2 super-phases / K-tile (4 barriers,
// was 8). Per-K-tile:
//  W1: rdA(af<-mq0) 8 + rdB(blo) 4 + rdB(bhi) 4; BAR; 32 MFMA (mq0 x both
//      n-quadrants); BAR.
//  W2: rdA(af<-mq1, regs reused) 8 + stage B(i+2) 4; lgkmcnt(0) PRE-barrier
//      (all A reads provably complete before any wave's stage-A DMA lands);
//      BAR; stage A(i+2) 4; vmcnt(8) [vmcnt(0) at i==nt-2]; 32 MFMA (mq1);
//      BAR.
// Hazards: B region last read in W1 < BAR-2 < stage-B issue; A region last
// read < BAR-3 < stage-A issue; vmcnt(8) retires exactly tile i+1's 8 loads
// (in-order: 8 of i+1 + 8 of i+2 outstanding). Same data/swizzle/per-acc
// K-order as round-10 -> bitwise-identical C. Rationale: 8 barriers/K-tile
// cost ~4600cy of the measured 6000cy/K-tile (reads 768 + MFMA 614); halving
// barrier count + doubling MFMA cluster size attacks exactly that.
// Dual-matrix mode: if A1 != nullptr (1024 blocks), j >= 64 per XCD computes
// C1 = A1 @ Bw1^T. mblocks/matrix = 128, N = 1024 (4 n-blocks).
// ---------------------------------------------------------------------------
__global__ __launch_bounds__(512, 2)
void gemm8(const bf16_t* __restrict__ A0, const bf16_t* __restrict__ Bw0,
           bf16_t* __restrict__ C0, const bf16_t* __restrict__ A1,
           const bf16_t* __restrict__ Bw1, bf16_t* __restrict__ C1,
           int N, int K) {
  __shared__ __attribute__((aligned(16))) char lds[131072];

  const int t = (int)threadIdx.x;
  const int lane = t & 63, w = t >> 6;
  const int wave_m = w >> 2, wave_n = w & 3;
  const int fr = lane & 15, fq = lane >> 4;
  const int bid = (int)blockIdx.x;
  const int x = bid & 7, j = bid >> 3;
  const bool second = (A1 != nullptr) && (j >= 64);
  const int jj = second ? (j - 64) : j;
  const bf16_t* A  = second ? A1 : A0;
  const bf16_t* Bw = second ? Bw1 : Bw0;
  bf16_t* C        = second ? C1 : C0;
  const int mb = x * 16 + (jj >> 2);          // S = 128/8 = 16
  const int nb = jj & 3;                      // N-block innermost
  const int brow = mb * 256, bcol = nb * 256;

  auto Aoff = [](int buf, int half) { return (buf * 2 + half) * 16384; };
  auto Boff = [](int buf, int half) { return 65536 + (buf * 2 + half) * 16384; };

  auto stage = [&](int tile, bool dA, bool dB) {
    const int buf = tile & 1;
    const int k0 = tile << 6;
#pragma unroll
    for (int n = 0; n < 2; ++n) {
      const int idx = n * 512 + t;
      const int row = idx >> 3;
      const int u = (idx & 7) ^ (row & 7);
      const int dst = (n * 8 + w) * 1024;     // wave-uniform LDS base
      if (dB) {
#pragma unroll
        for (int h = 0; h < 2; ++h)
          async16(lds + Boff(buf, h) + dst,
                  Bw + (size_t)(bcol + h * 128 + row) * K + k0 + u * 8);
      }
      if (dA) {
#pragma unroll
        for (int h = 0; h < 2; ++h)
          async16(lds + Aoff(buf, h) + dst,
                  A + (size_t)(brow + h * 128 + row) * K + k0 + u * 8);
      }
    }
  };

  bf16x8 af[4][2], blo[2][2], bhi[2][2];
  auto rdA = [&](int buf, int mq) {
    const char* base = lds + Aoff(buf, wave_m);
#pragma unroll
    for (int mf = 0; mf < 4; ++mf) {
      const int row = mq * 64 + mf * 16 + fr;
#pragma unroll
      for (int ks = 0; ks < 2; ++ks)
        af[mf][ks] = *(const bf16x8*)(base + row * 128 + (((ks * 4 + fq) ^ (row & 7)) << 4));
    }
  };
  auto rdB = [&](bf16x8 (&bf)[2][2], int buf, int nq) {
    const char* base = lds + Boff(buf, wave_n >> 1);
#pragma unroll
    for (int nf = 0; nf < 2; ++nf) {
      const int row = (wave_n & 1) * 64 + (nq * 2 + nf) * 16 + fr;
#pragma unroll
      for (int ks = 0; ks < 2; ++ks)
        bf[nf][ks] = *(const bf16x8*)(base + row * 128 + (((ks * 4 + fq) ^ (row & 7)) << 4));
    }
  };

  const f32x4 z = {0.f, 0.f, 0.f, 0.f};
  f32x4 acc[8][4];
#pragma unroll
  for (int m = 0; m < 8; ++m)
#pragma unroll
    for (int n = 0; n < 4; ++n) acc[m][n] = z;

  auto mma = [&](const bf16x8 (&bf)[2][2], int mq, int nq) {
#pragma unroll
    for (int mf = 0; mf < 4; ++mf)
#pragma unroll
      for (int nf = 0; nf < 2; ++nf)
#pragma unroll
        for (int ks = 0; ks < 2; ++ks)
          acc[mq * 4 + mf][nq * 2 + nf] = __builtin_amdgcn_mfma_f32_16x16x32_bf16(
              af[mf][ks], bf[nf][ks], acc[mq * 4 + mf][nq * 2 + nf], 0, 0, 0);
  };

  const int nt = K >> 6;                       // 16
  stage(0, true, true);
  stage(1, true, true);
  asm volatile("s_waitcnt vmcnt(8)" ::: "memory");
  BAR();

  for (int i = 0; i < nt; ++i) {
    const int buf = i & 1;
    // ---- W1: m-lo half, both n-quadrants (32 MFMA)
    rdA(buf, 0);
    rdB(blo, buf, 0);
    rdB(bhi, buf, 1);
    BAR();
    __builtin_amdgcn_s_setprio(1);
    mma(blo, 0, 0);
    mma(bhi, 0, 1);
    __builtin_amdgcn_s_setprio(0);
    BAR();
    // ---- W2: m-hi half (af regs reused), staging + counted vmcnt
    rdA(buf, 1);
    if (i + 2 < nt) stage(i + 2, false, true);           // B(i+2), 4 loads
    asm volatile("s_waitcnt lgkmcnt(0)" ::: "memory");   // A reads done pre-BAR
    BAR();
    if (i + 2 < nt) stage(i + 2, true, false);           // A(i+2), 4 loads
    if (i == nt - 2) {
      asm volatile("s_waitcnt vmcnt(0)" ::: "memory");
    } else if (i < nt - 2) {
      asm volatile("s_waitcnt vmcnt(8)" ::: "memory");   // retires tile i+1
    }
    __builtin_amdgcn_s_setprio(1);
    mma(blo, 1, 0);
    mma(bhi, 1, 1);
    __builtin_amdgcn_s_setprio(0);
    BAR();
  }

  // epilogue: C/D layout col=lane&15, row=(lane>>4)*4+reg
#pragma unroll
  for (int mf = 0; mf < 8; ++mf)
#pragma unroll
    for (int nf = 0; nf < 4; ++nf)
#pragma unroll
      for (int r = 0; r < 4; ++r) {
        const int row = brow + wave_m * 128 + mf * 16 + fq * 4 + r;
        const int col = bcol + wave_n * 64 + nf * 16 + fr;
        C[(size_t)row * N + col] = (__bf16)acc[mf][nf][r];
      }
}

// ---------------------------------------------------------------------------
// 2-phase DMA GEMM, bf16 A (round-5 proven). Used for Q-proj (plan B) / O-proj.
// ---------------------------------------------------------------------------
template<bool CF32>
__global__ __launch_bounds__(256)
void gemm_dma(const bf16_t* __restrict__ Ab, const bf16_t* __restrict__ Bw,
              void* __restrict__ Cp, int mblocks, int N, int K) {
  __shared__ __attribute__((aligned(16))) char AsB[2][8192];
  __shared__ __attribute__((aligned(16))) char BsB[2][8192];

  const int t = (int)threadIdx.x;
  const int lane = t & 63, wv = t >> 6;
  const int bid = (int)blockIdx.x;
  const int x = bid & 7;
  const int j = bid >> 3;
  const int S = mblocks >> 3;
  const int mb = (S > 0) ? (x * S + (j >> 3)) : (j >> 3);
  const int nb = j & 7;
  const int brow = mb * 128;
  const int bcol = nb * 128;
  const int wm = (wv >> 1) * 64, wn = (wv & 1) * 64;
  const int fr = lane & 15, fq = lane >> 4;

  auto stageT = [&](char* dst, const bf16_t* src, int rbase, int k0) {
    const int r4 = lane >> 2, u = lane & 3;
#pragma unroll
    for (int i = 0; i < 2; ++i) {
      const int seg = i * 4 + wv;
      const int row = seg * 16 + r4;
      const int col = ((u ^ ((row >> 1) & 3)) << 3);
      async16(dst + seg * 1024, src + (size_t)(rbase + row) * K + k0 + col);
    }
  };

  const f32x4 z = {0.f, 0.f, 0.f, 0.f};
  f32x4 acc[4][4];
#pragma unroll
  for (int m = 0; m < 4; ++m)
#pragma unroll
    for (int n = 0; n < 4; ++n) acc[m][n] = z;

  const int nt = K >> 5;
  stageT(AsB[0], Ab, brow, 0);
  stageT(BsB[0], Bw, bcol, 0);
  __syncthreads();
  int cur = 0;

  for (int tt = 0; tt < nt; ++tt) {
    if (tt + 1 < nt) {
      stageT(AsB[cur ^ 1], Ab, brow, (tt + 1) << 5);
      stageT(BsB[cur ^ 1], Bw, bcol, (tt + 1) << 5);
    }
    const char* Ac = AsB[cur];
    const char* Bc = BsB[cur];

    bf16x8 af[4], bfg[4];
#pragma unroll
    for (int m = 0; m < 4; ++m) {
      const int R = wm + m * 16 + fr;
      const int ph = (fq << 4) ^ (((R >> 1) & 3) << 4);
      af[m] = *(const bf16x8*)(Ac + R * 64 + ph);
    }
#pragma unroll
    for (int n = 0; n < 4; ++n) {
      const int R = wn + n * 16 + fr;
      const int ph = (fq << 4) ^ (((R >> 1) & 3) << 4);
      bfg[n] = *(const bf16x8*)(Bc + R * 64 + ph);
    }
#pragma unroll
    for (int m = 0; m < 4; ++m)
#pragma unroll
      for (int n = 0; n < 4; ++n)
        acc[m][n] = __builtin_amdgcn_mfma_f32_16x16x32_bf16(af[m], bfg[n], acc[m][n], 0, 0, 0);

    __syncthreads();
    cur ^= 1;
  }

  const int rb = fq * 4;
#pragma unroll
  for (int m = 0; m < 4; ++m)
#pragma unroll
    for (int n = 0; n < 4; ++n)
#pragma unroll
      for (int r = 0; r < 4; ++r) {
        const int row = brow + wm + m * 16 + rb + r;
        const int col = bcol + wn + n * 16 + fr;
        if constexpr (CF32)
          ((float*)Cp)[(size_t)row * N + col] = acc[m][n][r];
        else
          ((bf16_t*)Cp)[(size_t)row * N + col] = (__bf16)acc[m][n][r];
      }
}

// ---------------------------------------------------------------------------
// Fallback GEMM (round-1, fused f32->bf16 cvt, f32 weights) — only if ws tiny.
// ---------------------------------------------------------------------------
template<bool A_IS_F32, bool C_IS_F32>
__global__ __launch_bounds__(256)
void gemm_bt(const void* __restrict__ Ap, const float* __restrict__ Bw,
             void* __restrict__ Cp, int M, int N, int K) {
  (void)M;
  __shared__ bf16_t As[128][40];
  __shared__ bf16_t Bs[128][40];
  const int t = (int)threadIdx.x;
  const int lane = t & 63, wv = t >> 6;
  const int wm = (wv >> 1) * 64, wn = (wv & 1) * 64;
  const int brow = (int)blockIdx.y * 128, bcol = (int)blockIdx.x * 128;
  const int fr = lane & 15, fk = (lane >> 4) * 8;

  const f32x4 z = {0.f, 0.f, 0.f, 0.f};
  f32x4 acc[4][4];
#pragma unroll
  for (int m = 0; m < 4; ++m)
#pragma unroll
    for (int n = 0; n < 4; ++n) acc[m][n] = z;

  for (int k0 = 0; k0 < K; k0 += 32) {
    if constexpr (A_IS_F32) {
      const float* A = (const float*)Ap;
      const int tr = t >> 3, tc = (t & 7) * 4;
#pragma unroll
      for (int p = 0; p < 4; ++p) {
        const int r = p * 32 + tr;
        float4 v = *reinterpret_cast<const float4*>(A + (size_t)(brow + r) * K + k0 + tc);
        *reinterpret_cast<bf16x4*>(&As[r][tc]) = cvt4(v);
      }
    } else {
      const bf16_t* A = (const bf16_t*)Ap;
      const int tr = t >> 2, tc = (t & 3) * 8;
#pragma unroll
      for (int p = 0; p < 2; ++p) {
        const int r = p * 64 + tr;
        *reinterpret_cast<int4*>(&As[r][tc]) =
            *reinterpret_cast<const int4*>(A + (size_t)(brow + r) * K + k0 + tc);
      }
    }
    {
      const int tr = t >> 3, tc = (t & 7) * 4;
#pragma unroll
      for (int p = 0; p < 4; ++p) {
        const int r = p * 32 + tr;
        float4 v = *reinterpret_cast<const float4*>(Bw + (size_t)(bcol + r) * K + k0 + tc);
        *reinterpret_cast<bf16x4*>(&Bs[r][tc]) = cvt4(v);
      }
    }
    __syncthreads();
    bf16x8 af[4], bfr[4];
#pragma unroll
    for (int m = 0; m < 4; ++m)
      af[m] = *reinterpret_cast<const bf16x8*>(&As[wm + m * 16 + fr][fk]);
#pragma unroll
    for (int n = 0; n < 4; ++n)
      bfr[n] = *reinterpret_cast<const bf16x8*>(&Bs[wn + n * 16 + fr][fk]);
#pragma unroll
    for (int m = 0; m < 4; ++m)
#pragma unroll
      for (int n = 0; n < 4; ++n)
        acc[m][n] = __builtin_amdgcn_mfma_f32_16x16x32_bf16(af[m], bfr[n], acc[m][n], 0, 0, 0);
    __syncthreads();
  }
  const int rb = (lane >> 4) * 4;
#pragma unroll
  for (int m = 0; m < 4; ++m)
#pragma unroll
    for (int n = 0; n < 4; ++n)
#pragma unroll
      for (int r = 0; r < 4; ++r) {
        const int row = brow + wm + m * 16 + rb + r;
        const int col = bcol + wn + n * 16 + fr;
        if constexpr (C_IS_F32)
          ((float*)Cp)[(size_t)row * N + col] = acc[m][n][r];
        else
          ((bf16_t*)Cp)[(size_t)row * N + col] = (__bf16)acc[m][n][r];
      }
}

// ---------------------------------------------------------------------------
// Fused inverted attention (round-5 proven). Block = (b,h, l-chunk).
// ---------------------------------------------------------------------------
template<bool DIRECT>
__global__ __launch_bounds__(256)
void attn_inv(const bf16_t* __restrict__ qh, const bf16_t* __restrict__ kh,
              const bf16_t* __restrict__ vh, bf16_t* __restrict__ ao,
              float* __restrict__ part, int lcount) {
  const int bh = (int)blockIdx.x;
  const int b = bh >> 4, h = bh & 15;
  const int l_begin = (int)blockIdx.y * lcount;

  __shared__ bf16_t Qs[128][72];
  __shared__ bf16_t Ks[64][72];
  __shared__ bf16_t Vt[80][72];
  __shared__ bf16_t Ps[128][72];

  const int t = (int)threadIdx.x;
  const int lane = t & 63, w = t >> 6;
  const int fr = lane & 15, fq = lane >> 4;

  const bf16_t* qb = qh + (size_t)(b * CN) * CD + h * CDh;
#pragma unroll
  for (int p = 0; p < 4; ++p) {
    const int j = p * 256 + t;
    const int r = j >> 3, cc = (j & 7) * 8;
    *reinterpret_cast<int4*>(&Qs[r][cc]) =
        *reinterpret_cast<const int4*>(qb + (size_t)r * CD + cc);
  }
#pragma unroll
  for (int p = 0; p < 4; ++p) {
    const int j = p * 256 + t;
    const int r = 64 + (j >> 6), c = j & 63;
    Vt[r][c] = (r == 64) ? (__bf16)1.0f : (__bf16)0.0f;
  }

  const f32x4 z = {0.f, 0.f, 0.f, 0.f};
  f32x4 acc[2][5];
#pragma unroll
  for (int m = 0; m < 2; ++m)
#pragma unroll
    for (int n = 0; n < 5; ++n) acc[m][n] = z;

  for (int l0 = l_begin; l0 < l_begin + lcount; l0 += 64) {
    __syncthreads();
    const bf16_t* kb = kh + (size_t)(b * CL + l0) * CD + h * CDh;
    const bf16_t* vb = vh + (size_t)(b * CL + l0) * CD + h * CDh;
#pragma unroll
    for (int p = 0; p < 2; ++p) {
      const int j = p * 256 + t;
      const int r = j >> 3, cc = (j & 7) * 8;
      *reinterpret_cast<int4*>(&Ks[r][cc]) =
          *reinterpret_cast<const int4*>(kb + (size_t)r * CD + cc);
      int4 vv = *reinterpret_cast<const int4*>(vb + (size_t)r * CD + cc);
      const bf16_t* hp = reinterpret_cast<const bf16_t*>(&vv);
#pragma unroll
      for (int i = 0; i < 8; ++i) Vt[cc + i][r] = hp[i];
    }
    __syncthreads();

    f32x4 s[8];
#pragma unroll
    for (int m = 0; m < 8; ++m) s[m] = z;
#pragma unroll
    for (int ks = 0; ks < 2; ++ks) {
      bf16x8 bk = *reinterpret_cast<const bf16x8*>(&Ks[w * 16 + fr][ks * 32 + fq * 8]);
#pragma unroll
      for (int m = 0; m < 8; ++m) {
        bf16x8 aq = *reinterpret_cast<const bf16x8*>(&Qs[m * 16 + fr][ks * 32 + fq * 8]);
        s[m] = __builtin_amdgcn_mfma_f32_16x16x32_bf16(aq, bk, s[m], 0, 0, 0);
      }
    }

    float p[8][4];
    float mx = -3.0e38f;
#pragma unroll
    for (int m = 0; m < 8; ++m)
#pragma unroll
      for (int r = 0; r < 4; ++r) {
        const float xv = s[m][r] * 0.03125f;
        p[m][r] = xv;
        mx = fmaxf(mx, xv);
      }
    mx = fmaxf(mx, __shfl_xor(mx, 16));
    mx = fmaxf(mx, __shfl_xor(mx, 32));
    float sum = 0.f;
#pragma unroll
    for (int m = 0; m < 8; ++m)
#pragma unroll
      for (int r = 0; r < 4; ++r) {
        const float e = __expf(p[m][r] - mx);
        p[m][r] = e;
        sum += e;
      }
    sum += __shfl_xor(sum, 16);
    sum += __shfl_xor(sum, 32);
    const float inv = 1.0f / sum;
    const int pcol = w * 16 + fr;
#pragma unroll
    for (int m = 0; m < 8; ++m)
#pragma unroll
      for (int r = 0; r < 4; ++r)
        Ps[m * 16 + fq * 4 + r][pcol] = (__bf16)(p[m][r] * inv);
    __syncthreads();

#pragma unroll
    for (int ks = 0; ks < 2; ++ks) {
      bf16x8 pa[2];
#pragma unroll
      for (int m = 0; m < 2; ++m)
        pa[m] = *reinterpret_cast<const bf16x8*>(&Ps[w * 32 + m * 16 + fr][ks * 32 + fq * 8]);
#pragma unroll
      for (int n = 0; n < 5; ++n) {
        bf16x8 bv = *reinterpret_cast<const bf16x8*>(&Vt[n * 16 + fr][ks * 32 + fq * 8]);
#pragma unroll
        for (int m = 0; m < 2; ++m)
          acc[m][n] = __builtin_amdgcn_mfma_f32_16x16x32_bf16(pa[m], bv, acc[m][n], 0, 0, 0);
      }
    }
  }

  if constexpr (DIRECT) {
    bf16_t* ob = ao + (size_t)(b * CN) * CD + h * CDh;
#pragma unroll
    for (int m = 0; m < 2; ++m)
#pragma unroll
      for (int r = 0; r < 4; ++r) {
        const float R = __shfl(acc[m][4][r], lane & 48);
        const float invr = 1.0f / R;
        const int row = w * 32 + m * 16 + fq * 4 + r;
#pragma unroll
        for (int n = 0; n < 4; ++n) {
          const int col = n * 16 + fr;
          ob[(size_t)row * CD + col] = (__bf16)(acc[m][n][r] * invr);
        }
      }
  } else {
    float* pb = part + ((size_t)blockIdx.y * (CB * CH) + bh) * (size_t)(CN * 72);
#pragma unroll
    for (int m = 0; m < 2; ++m)
#pragma unroll
      for (int r = 0; r < 4; ++r) {
        const int row = w * 32 + m * 16 + fq * 4 + r;
#pragma unroll
        for (int n = 0; n < 4; ++n)
          pb[(size_t)row * 72 + n * 16 + fr] = acc[m][n][r];
        if (fr == 0) pb[(size_t)row * 72 + 64] = acc[m][4][r];
      }
  }
}

// reduce partials over splits, divide by R, write bf16 ao[b,n, h*64+c]
__global__ __launch_bounds__(256)
void attn_reduce(const float* __restrict__ part, bf16_t* __restrict__ ao, int nsplit) {
  const int idx = (int)blockIdx.x * 256 + (int)threadIdx.x;
  const int c = idx & 63;
  const int n = (idx >> 6) & 127;
  const int bh = idx >> 13;
  const float* p = part + (size_t)bh * (CN * 72) + (size_t)n * 72;
  const size_t sstr = (size_t)(CB * CH) * (CN * 72);
  float o = 0.f, r = 0.f;
  for (int s = 0; s < nsplit; ++s) {
    o += p[(size_t)s * sstr + c];
    r += p[(size_t)s * sstr + 64];
  }
  const int b = bh >> 4, h = bh & 15;
  ao[((size_t)(b * CN + n)) * CD + h * CDh + c] = (__bf16)(o / r);
}

extern "C" void kernel_launch(void* const* d_in, const int* in_sizes, int n_in,
                              void* d_out, int out_size, void* d_ws, size_t ws_size,
                              hipStream_t stream) {
  (void)in_sizes; (void)n_in; (void)out_size;
  const float* q  = (const float*)d_in[0];
  const float* k  = (const float*)d_in[1];
  const float* v  = (const float*)d_in[2];
  const float* Wq = (const float*)d_in[3];
  const float* Wk = (const float*)d_in[4];
  const float* Wv = (const float*)d_in[5];
  const float* Wo = (const float*)d_in[6];
  float* out = (float*)d_out;

  const size_t MiB = (size_t)1 << 20;
  const size_t QH_OFF = 0;
  const size_t KH_OFF = 2 * MiB;
  const size_t VH_OFF = KH_OFF + 64 * MiB;
  const size_t AO_OFF = VH_OFF + 64 * MiB;
  const size_t FIXED  = AO_OFF + 2 * MiB;  // 132 MiB
  if (ws_size < FIXED) return;

  char* ws = (char*)d_ws;
  bf16_t* qh = (bf16_t*)(ws + QH_OFF);
  bf16_t* kh = (bf16_t*)(ws + KH_OFF);
  bf16_t* vh = (bf16_t*)(ws + VH_OFF);
  bf16_t* ao = (bf16_t*)(ws + AO_OFF);

  const int M_q = CB * CN;          // 1024
  const int M_kv = CB * CL;         // 32768
  const int W4 = CD * CD / 4;       // 262144 float4s per weight
  const int A4_kv = M_kv * CD / 4;  // 8,388,608
  const int A4_q  = M_q * CD / 4;   // 262,144
  const size_t WS = (size_t)CD * CD;
  const size_t PB = (size_t)CB * CH * CN * 72 * 4;  // 4,718,592 B per split

  // ---- plan A (ws >= 270 MiB): fuse1 + dual gemm8, 5 dispatches ----
  const size_t WB4_OFF = FIXED;                  // 8 MiB: 4 bf16 weights
  const size_t QC_OFF  = WB4_OFF + 8 * MiB;      // 2 MiB (unused in plan A)
  const size_t KC_OFF  = QC_OFF + 2 * MiB;       // 64 MiB
  const size_t VC_OFF  = KC_OFF + 64 * MiB;      // 64 MiB
  const size_t NEED_A  = VC_OFF + 64 * MiB;      // 270 MiB

  if (ws_size >= NEED_A) {
    bf16_t* wb4 = (bf16_t*)(ws + WB4_OFF);
    bf16_t* kc  = (bf16_t*)(ws + KC_OFF);
    bf16_t* vc  = (bf16_t*)(ws + VC_OFF);
    float* part = (float*)(ws + KC_OFF);         // aliases kc (dead post-GEMM)

    const int NB_W = 4096;                        // 4 x 1024
    const int NB_KV = 2 * A4_kv / 256;            // 65536
    fuse1<<<64 + NB_W + NB_KV, 256, 0, stream>>>(q, k, v, Wq, Wk, Wv, Wo,
                                                 qh, wb4, kc, vc);

    gemm8<<<1024, 512, 0, stream>>>(kc, wb4 + WS, kh, vc, wb4 + 2 * WS, vh, CD, CD);

    attn_inv<false><<<dim3(CB * CH, 8), 256, 0, stream>>>(qh, kh, vh, ao, part, CL / 8);
    attn_reduce<<<(CB * CH * CN * 64) / 256, 256, 0, stream>>>(part, ao, 8);

    gemm_dma<true><<<(M_q / 128) * 8, 256, 0, stream>>>(ao, wb4 + 3 * WS, out, M_q / 128, CD, CD);
    return;
  }

  // ---- plan B (ws >= 200 MiB): round-8 flow ----
  const size_t WBUF_OFF = FIXED;
  const size_t QCB_OFF  = WBUF_OFF + 2 * MiB;
  const size_t KCB_OFF  = QCB_OFF + 2 * MiB;
  const size_t NEED_B   = KCB_OFF + 64 * MiB;    // 200 MiB

  if (ws_size >= NEED_B) {
    bf16_t* wbuf = (bf16_t*)(ws + WBUF_OFF);
    bf16_t* qc   = (bf16_t*)(ws + QCB_OFF);
    bf16_t* kc   = (bf16_t*)(ws + KCB_OFF);
    float*  part = (float*)(ws + KCB_OFF);

    cvt_f32_bf16<<<A4_q / 256, 256, 0, stream>>>(q, qc, A4_q);
    cvt_f32_bf16<<<W4 / 256, 256, 0, stream>>>(Wq, wbuf, W4);
    gemm_dma<false><<<(M_q / 128) * 8, 256, 0, stream>>>(qc, wbuf, qh, M_q / 128, CD, CD);

    cvt_f32_bf16<<<A4_kv / 256, 256, 0, stream>>>(k, kc, A4_kv);
    cvt_f32_bf16<<<W4 / 256, 256, 0, stream>>>(Wk, wbuf, W4);
    gemm8<<<512, 512, 0, stream>>>(kc, wbuf, kh, nullptr, nullptr, nullptr, CD, CD);

    cvt_f32_bf16<<<A4_kv / 256, 256, 0, stream>>>(v, kc, A4_kv);
    cvt_f32_bf16<<<W4 / 256, 256, 0, stream>>>(Wv, wbuf, W4);
    gemm8<<<512, 512, 0, stream>>>(kc, wbuf, vh, nullptr, nullptr, nullptr, CD, CD);

    attn_inv<false><<<dim3(CB * CH, 8), 256, 0, stream>>>(qh, kh, vh, ao, part, CL / 8);
    attn_reduce<<<(CB * CH * CN * 64) / 256, 256, 0, stream>>>(part, ao, 8);

    cvt_f32_bf16<<<W4 / 256, 256, 0, stream>>>(Wo, wbuf, W4);
    gemm_dma<true><<<(M_q / 128) * 8, 256, 0, stream>>>(ao, wbuf, out, M_q / 128, CD, CD);
    return;
  }

  // ---- minimal fallback (f32 weights, round-1 kernels) ----
  gemm_bt<true, false><<<dim3(CD / 128, M_q / 128),  256, 0, stream>>>(q, Wq, qh, M_q,  CD, CD);
  gemm_bt<true, false><<<dim3(CD / 128, M_kv / 128), 256, 0, stream>>>(k, Wk, kh, M_kv, CD, CD);
  gemm_bt<true, false><<<dim3(CD / 128, M_kv / 128), 256, 0, stream>>>(v, Wv, vh, M_kv, CD, CD);
  attn_inv<true><<<dim3(CB * CH, 1), 256, 0, stream>>>(qh, kh, vh, ao, nullptr, CL);
  gemm_bt<false, true><<<dim3(CD / 128, M_q / 128), 256, 0, stream>>>(ao, Wo, out, M_q, CD, CD);
}

// Round 15
// 329.451 us; speedup vs baseline: 1.0243x; 1.0243x over previous
//
#include <hip/hip_runtime.h>
#include <stdint.h>

typedef __bf16 bf16_t;
typedef __bf16 bf16x4 __attribute__((ext_vector_type(4)));
typedef __bf16 bf16x8 __attribute__((ext_vector_type(8)));
typedef float f32x4 __attribute__((ext_vector_type(4)));
typedef unsigned int u32;

// Problem constants (B, N, L, D, H) = (8, 128, 4096, 1024, 16)
constexpr int CB = 8, CN = 128, CL = 4096, CD = 1024, CH = 16, CDh = 64;

#define BAR()                                    \
  do {                                           \
    __asm__ volatile("" ::: "memory");           \
    __builtin_amdgcn_s_barrier();                \
    __asm__ volatile("" ::: "memory");           \
  } while (0)

__device__ __forceinline__ bf16x4 cvt4(float4 v) {
  bf16x4 r;
  r[0] = (__bf16)v.x; r[1] = (__bf16)v.y; r[2] = (__bf16)v.z; r[3] = (__bf16)v.w;
  return r;
}

// async global->LDS, 16 B per lane. LDS dest is wave-uniform base + lane*16.
__device__ __forceinline__ void async16(void* lds, const void* g) {
  __builtin_amdgcn_global_load_lds(
      (const __attribute__((address_space(1))) u32*)g,
      (__attribute__((address_space(3))) u32*)lds, 16, 0, 0);
}

// f32 -> bf16 elementwise, n4 = elems/4 (plan-B path)
__global__ __launch_bounds__(256) void cvt_f32_bf16(const float* __restrict__ in,
                                                    bf16_t* __restrict__ outp, int n4) {
  int i = (int)blockIdx.x * 256 + (int)threadIdx.x;
  if (i < n4) {
    float4 v = reinterpret_cast<const float4*>(in)[i];
    reinterpret_cast<bf16x4*>(outp)[i] = cvt4(v);
  }
}

// ---------------------------------------------------------------------------
// fuse1 (round 12, proven): ONE dispatch for three independent jobs.
//  blocks [0,64): Q-projection qh = bf16(q @ Wq^T) (round-1 body).
//  blocks [64, 64+4096): Wq,Wk,Wv,Wo -> wb4 (bf16).
//  blocks [64+4096, +65536): k,v -> kc,vc (bf16).
// ---------------------------------------------------------------------------
__global__ __launch_bounds__(256)
void fuse1(const float* __restrict__ q, const float* __restrict__ k,
           const float* __restrict__ v, const float* __restrict__ Wq,
           const float* __restrict__ Wk, const float* __restrict__ Wv,
           const float* __restrict__ Wo, bf16_t* __restrict__ qh,
           bf16_t* __restrict__ wb4, bf16_t* __restrict__ kc,
           bf16_t* __restrict__ vc) {
  const int bid = (int)blockIdx.x;
  const int t = (int)threadIdx.x;

  if (bid >= 64) {
    const int W4 = CD * CD / 4;
    const int A4_kv = CB * CL * CD / 4;
    if (bid < 64 + 4096) {
      const int widx = bid - 64;
      const int which = widx >> 10;
      const float* srcs[4] = {Wq, Wk, Wv, Wo};
      const int i = (widx & 1023) * 256 + t;
      reinterpret_cast<bf16x4*>(wb4 + (size_t)which * CD * CD)[i] =
          cvt4(reinterpret_cast<const float4*>(srcs[which])[i]);
    } else {
      const int i = (bid - 64 - 4096) * 256 + t;
      if (i < A4_kv)
        reinterpret_cast<bf16x4*>(kc)[i] = cvt4(reinterpret_cast<const float4*>(k)[i]);
      else
        reinterpret_cast<bf16x4*>(vc)[i - A4_kv] =
            cvt4(reinterpret_cast<const float4*>(v)[i - A4_kv]);
    }
    return;
  }

  __shared__ bf16_t As[128][40];
  __shared__ bf16_t Bs[128][40];
  const int lane = t & 63, wv = t >> 6;
  const int wm = (wv >> 1) * 64, wn = (wv & 1) * 64;
  const int brow = (bid >> 3) * 128, bcol = (bid & 7) * 128;
  const int fr = lane & 15, fk = (lane >> 4) * 8;
  const int K = CD;

  const f32x4 z = {0.f, 0.f, 0.f, 0.f};
  f32x4 acc[4][4];
#pragma unroll
  for (int m = 0; m < 4; ++m)
#pragma unroll
    for (int n = 0; n < 4; ++n) acc[m][n] = z;

  for (int k0 = 0; k0 < K; k0 += 32) {
    {
      const int tr = t >> 3, tc = (t & 7) * 4;
#pragma unroll
      for (int p = 0; p < 4; ++p) {
        const int r = p * 32 + tr;
        float4 va = *reinterpret_cast<const float4*>(q + (size_t)(brow + r) * K + k0 + tc);
        *reinterpret_cast<bf16x4*>(&As[r][tc]) = cvt4(va);
        float4 vb = *reinterpret_cast<const float4*>(Wq + (size_t)(bcol + r) * K + k0 + tc);
        *reinterpret_cast<bf16x4*>(&Bs[r][tc]) = cvt4(vb);
      }
    }
    __syncthreads();
    bf16x8 af[4], bfr[4];
#pragma unroll
    for (int m = 0; m < 4; ++m)
      af[m] = *reinterpret_cast<const bf16x8*>(&As[wm + m * 16 + fr][fk]);
#pragma unroll
    for (int n = 0; n < 4; ++n)
      bfr[n] = *reinterpret_cast<const bf16x8*>(&Bs[wn + n * 16 + fr][fk]);
#pragma unroll
    for (int m = 0; m < 4; ++m)
#pragma unroll
      for (int n = 0; n < 4; ++n)
        acc[m][n] = __builtin_amdgcn_mfma_f32_16x16x32_bf16(af[m], bfr[n], acc[m][n], 0, 0, 0);
    __syncthreads();
  }
  const int rb = (lane >> 4) * 4;
#pragma unroll
  for (int m = 0; m < 4; ++m)
#pragma unroll
    for (int n = 0; n < 4; ++n)
#pragma unroll
      for (int r = 0; r < 4; ++r) {
        const int row = brow + wm + m * 16 + rb + r;
        const int col = bcol + wn + n * 16 + fr;
        qh[(size_t)row * CD + col] = (__bf16)acc[m][n][r];
      }
}

// ---------------------------------------------------------------------------
// 8-phase 256x256xBK64 bf16 GEMM (T2+T3+T4+T5) — EXACT round-10 variant
// (854 TF measured; r11 ks-outer/read-ahead and r14 4-barrier restructures
// both A/B'd null-to-negative and are reverted).
// C = A @ Bw^T.  Dual-matrix mode: if A1 != nullptr (1024 blocks), j >= 64
// within each XCD computes C1 = A1 @ Bw1^T. mblocks/matrix = 128, N = 1024.
// Staging: stage tile i+2 at ph3(B)/ph4(A); vmcnt(8) at ph4 retires tile
// i+1's 8 loads, leaves tile i+2's in flight (never drains to 0 mid-loop).
// ---------------------------------------------------------------------------
__global__ __launch_bounds__(512, 2)
void gemm8(const bf16_t* __restrict__ A0, const bf16_t* __restrict__ Bw0,
           bf16_t* __restrict__ C0, const bf16_t* __restrict__ A1,
           const bf16_t* __restrict__ Bw1, bf16_t* __restrict__ C1,
           int N, int K) {
  __shared__ __attribute__((aligned(16))) char lds[131072];

  const int t = (int)threadIdx.x;
  const int lane = t & 63, w = t >> 6;
  const int wave_m = w >> 2, wave_n = w & 3;
  const int fr = lane & 15, fq = lane >> 4;
  const int bid = (int)blockIdx.x;
  const int x = bid & 7, j = bid >> 3;
  const bool second = (A1 != nullptr) && (j >= 64);
  const int jj = second ? (j - 64) : j;
  const bf16_t* A  = second ? A1 : A0;
  const bf16_t* Bw = second ? Bw1 : Bw0;
  bf16_t* C        = second ? C1 : C0;
  const int mb = x * 16 + (jj >> 2);          // S = 128/8 = 16
  const int nb = jj & 3;                      // N-block innermost
  const int brow = mb * 256, bcol = nb * 256;

  auto Aoff = [](int buf, int half) { return (buf * 2 + half) * 16384; };
  auto Boff = [](int buf, int half) { return 65536 + (buf * 2 + half) * 16384; };

  auto stage = [&](int tile, bool dA, bool dB) {
    const int buf = tile & 1;
    const int k0 = tile << 6;
#pragma unroll
    for (int n = 0; n < 2; ++n) {
      const int idx = n * 512 + t;
      const int row = idx >> 3;
      const int u = (idx & 7) ^ (row & 7);
      const int dst = (n * 8 + w) * 1024;     // wave-uniform LDS base
      if (dB) {
#pragma unroll
        for (int h = 0; h < 2; ++h)
          async16(lds + Boff(buf, h) + dst,
                  Bw + (size_t)(bcol + h * 128 + row) * K + k0 + u * 8);
      }
      if (dA) {
#pragma unroll
        for (int h = 0; h < 2; ++h)
          async16(lds + Aoff(buf, h) + dst,
                  A + (size_t)(brow + h * 128 + row) * K + k0 + u * 8);
      }
    }
  };

  bf16x8 af[4][2], blo[2][2], bhi[2][2];
  auto rdA = [&](int buf, int mq) {
    const char* base = lds + Aoff(buf, wave_m);
#pragma unroll
    for (int mf = 0; mf < 4; ++mf) {
      const int row = mq * 64 + mf * 16 + fr;
#pragma unroll
      for (int ks = 0; ks < 2; ++ks)
        af[mf][ks] = *(const bf16x8*)(base + row * 128 + (((ks * 4 + fq) ^ (row & 7)) << 4));
    }
  };
  auto rdB = [&](bf16x8 (&bf)[2][2], int buf, int nq) {
    const char* base = lds + Boff(buf, wave_n >> 1);
#pragma unroll
    for (int nf = 0; nf < 2; ++nf) {
      const int row = (wave_n & 1) * 64 + (nq * 2 + nf) * 16 + fr;
#pragma unroll
      for (int ks = 0; ks < 2; ++ks)
        bf[nf][ks] = *(const bf16x8*)(base + row * 128 + (((ks * 4 + fq) ^ (row & 7)) << 4));
    }
  };

  const f32x4 z = {0.f, 0.f, 0.f, 0.f};
  f32x4 acc[8][4];
#pragma unroll
  for (int m = 0; m < 8; ++m)
#pragma unroll
    for (int n = 0; n < 4; ++n) acc[m][n] = z;

  auto mma = [&](const bf16x8 (&bf)[2][2], int mq, int nq) {
    __builtin_amdgcn_s_setprio(1);
#pragma unroll
    for (int mf = 0; mf < 4; ++mf)
#pragma unroll
      for (int nf = 0; nf < 2; ++nf)
#pragma unroll
        for (int ks = 0; ks < 2; ++ks)
          acc[mq * 4 + mf][nq * 2 + nf] = __builtin_amdgcn_mfma_f32_16x16x32_bf16(
              af[mf][ks], bf[nf][ks], acc[mq * 4 + mf][nq * 2 + nf], 0, 0, 0);
    __builtin_amdgcn_s_setprio(0);
  };

  const int nt = K >> 6;                       // 16
  stage(0, true, true);
  stage(1, true, true);
  asm volatile("s_waitcnt vmcnt(8)" ::: "memory");
  BAR();

  for (int i = 0; i < nt; ++i) {
    const int buf = i & 1;
    // ---- ph1: quadrant (m-lo, n-lo)
    rdA(buf, 0);
    rdB(blo, buf, 0);
    BAR();
    mma(blo, 0, 0);
    BAR();
    // ---- ph2: (m-lo, n-hi)
    rdB(bhi, buf, 1);
    BAR();
    mma(bhi, 0, 1);
    BAR();
    // ---- ph3: (m-hi, n-lo); stage B halves of tile i+2
    rdA(buf, 1);
    if (i + 2 < nt) stage(i + 2, false, true);
    BAR();
    mma(blo, 1, 0);
    BAR();
    // ---- ph4: (m-hi, n-hi); stage A halves of tile i+2; counted wait
    if (i + 2 < nt) stage(i + 2, true, false);
    if (i == nt - 2) {
      asm volatile("s_waitcnt vmcnt(0)" ::: "memory");
    } else if (i < nt - 2) {
      asm volatile("s_waitcnt vmcnt(8)" ::: "memory");
    }
    BAR();
    mma(bhi, 1, 1);
    BAR();
  }

  // epilogue: C/D layout col=lane&15, row=(lane>>4)*4+reg
#pragma unroll
  for (int mf = 0; mf < 8; ++mf)
#pragma unroll
    for (int nf = 0; nf < 4; ++nf)
#pragma unroll
      for (int r = 0; r < 4; ++r) {
        const int row = brow + wave_m * 128 + mf * 16 + fq * 4 + r;
        const int col = bcol + wave_n * 64 + nf * 16 + fr;
        C[(size_t)row * N + col] = (__bf16)acc[mf][nf][r];
      }
}

// ---------------------------------------------------------------------------
// 2-phase DMA GEMM, bf16 A (round-5 proven). Used for Q-proj (plan B) / O-proj.
// ---------------------------------------------------------------------------
template<bool CF32>
__global__ __launch_bounds__(256)
void gemm_dma(const bf16_t* __restrict__ Ab, const bf16_t* __restrict__ Bw,
              void* __restrict__ Cp, int mblocks, int N, int K) {
  __shared__ __attribute__((aligned(16))) char AsB[2][8192];
  __shared__ __attribute__((aligned(16))) char BsB[2][8192];

  const int t = (int)threadIdx.x;
  const int lane = t & 63, wv = t >> 6;
  const int bid = (int)blockIdx.x;
  const int x = bid & 7;
  const int j = bid >> 3;
  const int S = mblocks >> 3;
  const int mb = (S > 0) ? (x * S + (j >> 3)) : (j >> 3);
  const int nb = j & 7;
  const int brow = mb * 128;
  const int bcol = nb * 128;
  const int wm = (wv >> 1) * 64, wn = (wv & 1) * 64;
  const int fr = lane & 15, fq = lane >> 4;

  auto stageT = [&](char* dst, const bf16_t* src, int rbase, int k0) {
    const int r4 = lane >> 2, u = lane & 3;
#pragma unroll
    for (int i = 0; i < 2; ++i) {
      const int seg = i * 4 + wv;
      const int row = seg * 16 + r4;
      const int col = ((u ^ ((row >> 1) & 3)) << 3);
      async16(dst + seg * 1024, src + (size_t)(rbase + row) * K + k0 + col);
    }
  };

  const f32x4 z = {0.f, 0.f, 0.f, 0.f};
  f32x4 acc[4][4];
#pragma unroll
  for (int m = 0; m < 4; ++m)
#pragma unroll
    for (int n = 0; n < 4; ++n) acc[m][n] = z;

  const int nt = K >> 5;
  stageT(AsB[0], Ab, brow, 0);
  stageT(BsB[0], Bw, bcol, 0);
  __syncthreads();
  int cur = 0;

  for (int tt = 0; tt < nt; ++tt) {
    if (tt + 1 < nt) {
      stageT(AsB[cur ^ 1], Ab, brow, (tt + 1) << 5);
      stageT(BsB[cur ^ 1], Bw, bcol, (tt + 1) << 5);
    }
    const char* Ac = AsB[cur];
    const char* Bc = BsB[cur];

    bf16x8 af[4], bfg[4];
#pragma unroll
    for (int m = 0; m < 4; ++m) {
      const int R = wm + m * 16 + fr;
      const int ph = (fq << 4) ^ (((R >> 1) & 3) << 4);
      af[m] = *(const bf16x8*)(Ac + R * 64 + ph);
    }
#pragma unroll
    for (int n = 0; n < 4; ++n) {
      const int R = wn + n * 16 + fr;
      const int ph = (fq << 4) ^ (((R >> 1) & 3) << 4);
      bfg[n] = *(const bf16x8*)(Bc + R * 64 + ph);
    }
#pragma unroll
    for (int m = 0; m < 4; ++m)
#pragma unroll
      for (int n = 0; n < 4; ++n)
        acc[m][n] = __builtin_amdgcn_mfma_f32_16x16x32_bf16(af[m], bfg[n], acc[m][n], 0, 0, 0);

    __syncthreads();
    cur ^= 1;
  }

  const int rb = fq * 4;
#pragma unroll
  for (int m = 0; m < 4; ++m)
#pragma unroll
    for (int n = 0; n < 4; ++n)
#pragma unroll
      for (int r = 0; r < 4; ++r) {
        const int row = brow + wm + m * 16 + rb + r;
        const int col = bcol + wn + n * 16 + fr;
        if constexpr (CF32)
          ((float*)Cp)[(size_t)row * N + col] = acc[m][n][r];
        else
          ((bf16_t*)Cp)[(size_t)row * N + col] = (__bf16)acc[m][n][r];
      }
}

// ---------------------------------------------------------------------------
// Fallback GEMM (round-1, fused f32->bf16 cvt, f32 weights) — only if ws tiny.
// ---------------------------------------------------------------------------
template<bool A_IS_F32, bool C_IS_F32>
__global__ __launch_bounds__(256)
void gemm_bt(const void* __restrict__ Ap, const float* __restrict__ Bw,
             void* __restrict__ Cp, int M, int N, int K) {
  (void)M;
  __shared__ bf16_t As[128][40];
  __shared__ bf16_t Bs[128][40];
  const int t = (int)threadIdx.x;
  const int lane = t & 63, wv = t >> 6;
  const int wm = (wv >> 1) * 64, wn = (wv & 1) * 64;
  const int brow = (int)blockIdx.y * 128, bcol = (int)blockIdx.x * 128;
  const int fr = lane & 15, fk = (lane >> 4) * 8;

  const f32x4 z = {0.f, 0.f, 0.f, 0.f};
  f32x4 acc[4][4];
#pragma unroll
  for (int m = 0; m < 4; ++m)
#pragma unroll
    for (int n = 0; n < 4; ++n) acc[m][n] = z;

  for (int k0 = 0; k0 < K; k0 += 32) {
    if constexpr (A_IS_F32) {
      const float* A = (const float*)Ap;
      const int tr = t >> 3, tc = (t & 7) * 4;
#pragma unroll
      for (int p = 0; p < 4; ++p) {
        const int r = p * 32 + tr;
        float4 v = *reinterpret_cast<const float4*>(A + (size_t)(brow + r) * K + k0 + tc);
        *reinterpret_cast<bf16x4*>(&As[r][tc]) = cvt4(v);
      }
    } else {
      const bf16_t* A = (const bf16_t*)Ap;
      const int tr = t >> 2, tc = (t & 3) * 8;
#pragma unroll
      for (int p = 0; p < 2; ++p) {
        const int r = p * 64 + tr;
        *reinterpret_cast<int4*>(&As[r][tc]) =
            *reinterpret_cast<const int4*>(A + (size_t)(brow + r) * K + k0 + tc);
      }
    }
    {
      const int tr = t >> 3, tc = (t & 7) * 4;
#pragma unroll
      for (int p = 0; p < 4; ++p) {
        const int r = p * 32 + tr;
        float4 v = *reinterpret_cast<const float4*>(Bw + (size_t)(bcol + r) * K + k0 + tc);
        *reinterpret_cast<bf16x4*>(&Bs[r][tc]) = cvt4(v);
      }
    }
    __syncthreads();
    bf16x8 af[4], bfr[4];
#pragma unroll
    for (int m = 0; m < 4; ++m)
      af[m] = *reinterpret_cast<const bf16x8*>(&As[wm + m * 16 + fr][fk]);
#pragma unroll
    for (int n = 0; n < 4; ++n)
      bfr[n] = *reinterpret_cast<const bf16x8*>(&Bs[wn + n * 16 + fr][fk]);
#pragma unroll
    for (int m = 0; m < 4; ++m)
#pragma unroll
      for (int n = 0; n < 4; ++n)
        acc[m][n] = __builtin_amdgcn_mfma_f32_16x16x32_bf16(af[m], bfr[n], acc[m][n], 0, 0, 0);
    __syncthreads();
  }
  const int rb = (lane >> 4) * 4;
#pragma unroll
  for (int m = 0; m < 4; ++m)
#pragma unroll
    for (int n = 0; n < 4; ++n)
#pragma unroll
      for (int r = 0; r < 4; ++r) {
        const int row = brow + wm + m * 16 + rb + r;
        const int col = bcol + wn + n * 16 + fr;
        if constexpr (C_IS_F32)
          ((float*)Cp)[(size_t)row * N + col] = acc[m][n][r];
        else
          ((bf16_t*)Cp)[(size_t)row * N + col] = (__bf16)acc[m][n][r];
      }
}

// ---------------------------------------------------------------------------
// Fused inverted attention (round-5 proven). Block = (b,h, l-chunk).
// ---------------------------------------------------------------------------
template<bool DIRECT>
__global__ __launch_bounds__(256)
void attn_inv(const bf16_t* __restrict__ qh, const bf16_t* __restrict__ kh,
              const bf16_t* __restrict__ vh, bf16_t* __restrict__ ao,
              float* __restrict__ part, int lcount) {
  const int bh = (int)blockIdx.x;
  const int b = bh >> 4, h = bh & 15;
  const int l_begin = (int)blockIdx.y * lcount;

  __shared__ bf16_t Qs[128][72];
  __shared__ bf16_t Ks[64][72];
  __shared__ bf16_t Vt[80][72];
  __shared__ bf16_t Ps[128][72];

  const int t = (int)threadIdx.x;
  const int lane = t & 63, w = t >> 6;
  const int fr = lane & 15, fq = lane >> 4;

  const bf16_t* qb = qh + (size_t)(b * CN) * CD + h * CDh;
#pragma unroll
  for (int p = 0; p < 4; ++p) {
    const int j = p * 256 + t;
    const int r = j >> 3, cc = (j & 7) * 8;
    *reinterpret_cast<int4*>(&Qs[r][cc]) =
        *reinterpret_cast<const int4*>(qb + (size_t)r * CD + cc);
  }
#pragma unroll
  for (int p = 0; p < 4; ++p) {
    const int j = p * 256 + t;
    const int r = 64 + (j >> 6), c = j & 63;
    Vt[r][c] = (r == 64) ? (__bf16)1.0f : (__bf16)0.0f;
  }

  const f32x4 z = {0.f, 0.f, 0.f, 0.f};
  f32x4 acc[2][5];
#pragma unroll
  for (int m = 0; m < 2; ++m)
#pragma unroll
    for (int n = 0; n < 5; ++n) acc[m][n] = z;

  for (int l0 = l_begin; l0 < l_begin + lcount; l0 += 64) {
    __syncthreads();
    const bf16_t* kb = kh + (size_t)(b * CL + l0) * CD + h * CDh;
    const bf16_t* vb = vh + (size_t)(b * CL + l0) * CD + h * CDh;
#pragma unroll
    for (int p = 0; p < 2; ++p) {
      const int j = p * 256 + t;
      const int r = j >> 3, cc = (j & 7) * 8;
      *reinterpret_cast<int4*>(&Ks[r][cc]) =
          *reinterpret_cast<const int4*>(kb + (size_t)r * CD + cc);
      int4 vv = *reinterpret_cast<const int4*>(vb + (size_t)r * CD + cc);
      const bf16_t* hp = reinterpret_cast<const bf16_t*>(&vv);
#pragma unroll
      for (int i = 0; i < 8; ++i) Vt[cc + i][r] = hp[i];
    }
    __syncthreads();

    f32x4 s[8];
#pragma unroll
    for (int m = 0; m < 8; ++m) s[m] = z;
#pragma unroll
    for (int ks = 0; ks < 2; ++ks) {
      bf16x8 bk = *reinterpret_cast<const bf16x8*>(&Ks[w * 16 + fr][ks * 32 + fq * 8]);
#pragma unroll
      for (int m = 0; m < 8; ++m) {
        bf16x8 aq = *reinterpret_cast<const bf16x8*>(&Qs[m * 16 + fr][ks * 32 + fq * 8]);
        s[m] = __builtin_amdgcn_mfma_f32_16x16x32_bf16(aq, bk, s[m], 0, 0, 0);
      }
    }

    float p[8][4];
    float mx = -3.0e38f;
#pragma unroll
    for (int m = 0; m < 8; ++m)
#pragma unroll
      for (int r = 0; r < 4; ++r) {
        const float xv = s[m][r] * 0.03125f;
        p[m][r] = xv;
        mx = fmaxf(mx, xv);
      }
    mx = fmaxf(mx, __shfl_xor(mx, 16));
    mx = fmaxf(mx, __shfl_xor(mx, 32));
    float sum = 0.f;
#pragma unroll
    for (int m = 0; m < 8; ++m)
#pragma unroll
      for (int r = 0; r < 4; ++r) {
        const float e = __expf(p[m][r] - mx);
        p[m][r] = e;
        sum += e;
      }
    sum += __shfl_xor(sum, 16);
    sum += __shfl_xor(sum, 32);
    const float inv = 1.0f / sum;
    const int pcol = w * 16 + fr;
#pragma unroll
    for (int m = 0; m < 8; ++m)
#pragma unroll
      for (int r = 0; r < 4; ++r)
        Ps[m * 16 + fq * 4 + r][pcol] = (__bf16)(p[m][r] * inv);
    __syncthreads();

#pragma unroll
    for (int ks = 0; ks < 2; ++ks) {
      bf16x8 pa[2];
#pragma unroll
      for (int m = 0; m < 2; ++m)
        pa[m] = *reinterpret_cast<const bf16x8*>(&Ps[w * 32 + m * 16 + fr][ks * 32 + fq * 8]);
#pragma unroll
      for (int n = 0; n < 5; ++n) {
        bf16x8 bv = *reinterpret_cast<const bf16x8*>(&Vt[n * 16 + fr][ks * 32 + fq * 8]);
#pragma unroll
        for (int m = 0; m < 2; ++m)
          acc[m][n] = __builtin_amdgcn_mfma_f32_16x16x32_bf16(pa[m], bv, acc[m][n], 0, 0, 0);
      }
    }
  }

  if constexpr (DIRECT) {
    bf16_t* ob = ao + (size_t)(b * CN) * CD + h * CDh;
#pragma unroll
    for (int m = 0; m < 2; ++m)
#pragma unroll
      for (int r = 0; r < 4; ++r) {
        const float R = __shfl(acc[m][4][r], lane & 48);
        const float invr = 1.0f / R;
        const int row = w * 32 + m * 16 + fq * 4 + r;
#pragma unroll
        for (int n = 0; n < 4; ++n) {
          const int col = n * 16 + fr;
          ob[(size_t)row * CD + col] = (__bf16)(acc[m][n][r] * invr);
        }
      }
  } else {
    float* pb = part + ((size_t)blockIdx.y * (CB * CH) + bh) * (size_t)(CN * 72);
#pragma unroll
    for (int m = 0; m < 2; ++m)
#pragma unroll
      for (int r = 0; r < 4; ++r) {
        const int row = w * 32 + m * 16 + fq * 4 + r;
#pragma unroll
        for (int n = 0; n < 4; ++n)
          pb[(size_t)row * 72 + n * 16 + fr] = acc[m][n][r];
        if (fr == 0) pb[(size_t)row * 72 + 64] = acc[m][4][r];
      }
  }
}

// reduce partials over splits, divide by R, write bf16 ao[b,n, h*64+c]
__global__ __launch_bounds__(256)
void attn_reduce(const float* __restrict__ part, bf16_t* __restrict__ ao, int nsplit) {
  const int idx = (int)blockIdx.x * 256 + (int)threadIdx.x;
  const int c = idx & 63;
  const int n = (idx >> 6) & 127;
  const int bh = idx >> 13;
  const float* p = part + (size_t)bh * (CN * 72) + (size_t)n * 72;
  const size_t sstr = (size_t)(CB * CH) * (CN * 72);
  float o = 0.f, r = 0.f;
  for (int s = 0; s < nsplit; ++s) {
    o += p[(size_t)s * sstr + c];
    r += p[(size_t)s * sstr + 64];
  }
  const int b = bh >> 4, h = bh & 15;
  ao[((size_t)(b * CN + n)) * CD + h * CDh + c] = (__bf16)(o / r);
}

extern "C" void kernel_launch(void* const* d_in, const int* in_sizes, int n_in,
                              void* d_out, int out_size, void* d_ws, size_t ws_size,
                              hipStream_t stream) {
  (void)in_sizes; (void)n_in; (void)out_size;
  const float* q  = (const float*)d_in[0];
  const float* k  = (const float*)d_in[1];
  const float* v  = (const float*)d_in[2];
  const float* Wq = (const float*)d_in[3];
  const float* Wk = (const float*)d_in[4];
  const float* Wv = (const float*)d_in[5];
  const float* Wo = (const float*)d_in[6];
  float* out = (float*)d_out;

  const size_t MiB = (size_t)1 << 20;
  const size_t QH_OFF = 0;
  const size_t KH_OFF = 2 * MiB;
  const size_t VH_OFF = KH_OFF + 64 * MiB;
  const size_t AO_OFF = VH_OFF + 64 * MiB;
  const size_t FIXED  = AO_OFF + 2 * MiB;  // 132 MiB
  if (ws_size < FIXED) return;

  char* ws = (char*)d_ws;
  bf16_t* qh = (bf16_t*)(ws + QH_OFF);
  bf16_t* kh = (bf16_t*)(ws + KH_OFF);
  bf16_t* vh = (bf16_t*)(ws + VH_OFF);
  bf16_t* ao = (bf16_t*)(ws + AO_OFF);

  const int M_q = CB * CN;          // 1024
  const int M_kv = CB * CL;         // 32768
  const int W4 = CD * CD / 4;       // 262144 float4s per weight
  const int A4_kv = M_kv * CD / 4;  // 8,388,608
  const int A4_q  = M_q * CD / 4;   // 262,144
  const size_t WS = (size_t)CD * CD;
  const size_t PB = (size_t)CB * CH * CN * 72 * 4;  // 4,718,592 B per split

  // ---- plan A (ws >= 270 MiB): fuse1 + dual gemm8, 5 dispatches ----
  const size_t WB4_OFF = FIXED;                  // 8 MiB: 4 bf16 weights
  const size_t QC_OFF  = WB4_OFF + 8 * MiB;      // 2 MiB (unused in plan A)
  const size_t KC_OFF  = QC_OFF + 2 * MiB;       // 64 MiB
  const size_t VC_OFF  = KC_OFF + 64 * MiB;      // 64 MiB
  const size_t NEED_A  = VC_OFF + 64 * MiB;      // 270 MiB

  if (ws_size >= NEED_A) {
    bf16_t* wb4 = (bf16_t*)(ws + WB4_OFF);
    bf16_t* kc  = (bf16_t*)(ws + KC_OFF);
    bf16_t* vc  = (bf16_t*)(ws + VC_OFF);
    float* part = (float*)(ws + KC_OFF);         // aliases kc (dead post-GEMM)

    const int NB_W = 4096;                        // 4 x 1024
    const int NB_KV = 2 * A4_kv / 256;            // 65536
    fuse1<<<64 + NB_W + NB_KV, 256, 0, stream>>>(q, k, v, Wq, Wk, Wv, Wo,
                                                 qh, wb4, kc, vc);

    gemm8<<<1024, 512, 0, stream>>>(kc, wb4 + WS, kh, vc, wb4 + 2 * WS, vh, CD, CD);

    // attention: nsplit=4 (512 blocks = 256 CU x 2 blocks/CU, one full wave;
    // halves the part-buffer round trip vs nsplit=8)
    attn_inv<false><<<dim3(CB * CH, 4), 256, 0, stream>>>(qh, kh, vh, ao, part, CL / 4);
    attn_reduce<<<(CB * CH * CN * 64) / 256, 256, 0, stream>>>(part, ao, 4);

    gemm_dma<true><<<(M_q / 128) * 8, 256, 0, stream>>>(ao, wb4 + 3 * WS, out, M_q / 128, CD, CD);
    return;
  }

  // ---- plan B (ws >= 200 MiB): round-8 flow ----
  const size_t WBUF_OFF = FIXED;
  const size_t QCB_OFF  = WBUF_OFF + 2 * MiB;
  const size_t KCB_OFF  = QCB_OFF + 2 * MiB;
  const size_t NEED_B   = KCB_OFF + 64 * MiB;    // 200 MiB

  if (ws_size >= NEED_B) {
    bf16_t* wbuf = (bf16_t*)(ws + WBUF_OFF);
    bf16_t* qc   = (bf16_t*)(ws + QCB_OFF);
    bf16_t* kc   = (bf16_t*)(ws + KCB_OFF);
    float*  part = (float*)(ws + KCB_OFF);

    cvt_f32_bf16<<<A4_q / 256, 256, 0, stream>>>(q, qc, A4_q);
    cvt_f32_bf16<<<W4 / 256, 256, 0, stream>>>(Wq, wbuf, W4);
    gemm_dma<false><<<(M_q / 128) * 8, 256, 0, stream>>>(qc, wbuf, qh, M_q / 128, CD, CD);

    cvt_f32_bf16<<<A4_kv / 256, 256, 0, stream>>>(k, kc, A4_kv);
    cvt_f32_bf16<<<W4 / 256, 256, 0, stream>>>(Wk, wbuf, W4);
    gemm8<<<512, 512, 0, stream>>>(kc, wbuf, kh, nullptr, nullptr, nullptr, CD, CD);

    cvt_f32_bf16<<<A4_kv / 256, 256, 0, stream>>>(v, kc, A4_kv);
    cvt_f32_bf16<<<W4 / 256, 256, 0, stream>>>(Wv, wbuf, W4);
    gemm8<<<512, 512, 0, stream>>>(kc, wbuf, vh, nullptr, nullptr, nullptr, CD, CD);

    attn_inv<false><<<dim3(CB * CH, 4), 256, 0, stream>>>(qh, kh, vh, ao, part, CL / 4);
    attn_reduce<<<(CB * CH * CN * 64) / 256, 256, 0, stream>>>(part, ao, 4);

    cvt_f32_bf16<<<W4 / 256, 256, 0, stream>>>(Wo, wbuf, W4);
    gemm_dma<true><<<(M_q / 128) * 8, 256, 0, stream>>>(ao, wbuf, out, M_q / 128, CD, CD);
    return;
  }

  // ---- minimal fallback (f32 weights, round-1 kernels) ----
  gemm_bt<true, false><<<dim3(CD / 128, M_q / 128),  256, 0, stream>>>(q, Wq, qh, M_q,  CD, CD);
  gemm_bt<true, false><<<dim3(CD / 128, M_kv / 128), 256, 0, stream>>>(k, Wk, kh, M_kv, CD, CD);
  gemm_bt<true, false><<<dim3(CD / 128, M_kv / 128), 256, 0, stream>>>(v, Wv, vh, M_kv, CD, CD);
  attn_inv<true><<<dim3(CB * CH, 1), 256, 0, stream>>>(qh, kh, vh, ao, nullptr, CL);
  gemm_bt<false, true><<<dim3(CD / 128, M_q / 128), 256, 0, stream>>>(ao, Wo, out, M_q, CD, CD);
}